// Round 8
// baseline (387.747 us; speedup 1.0000x reference)
//
#include <hip/hip_runtime.h>

typedef __attribute__((ext_vector_type(8))) short bf16x8;
typedef __attribute__((ext_vector_type(4))) float f32x4;
typedef __attribute__((ext_vector_type(8))) unsigned short u16x8;

#define DEVINL __device__ __forceinline__
#define AS1 __attribute__((address_space(1)))
#define AS3 __attribute__((address_space(3)))

constexpr int NI = 256;   // input channels (K)
constexpr int NO = 256;   // output channels
constexpr int NC = 120;   // irrep feature width
constexpr int WELEMS = 56 * NO * NI;                 // 3,670,016
constexpr size_t XT_ELEMS = (size_t)NC * 1024 * NI;  // 31,457,280

DEVINL ushort f2bf(float x) {   // round-to-nearest-even fp32 -> bf16 bits
  unsigned u = __float_as_uint(x);
  u += 0x7FFFu + ((u >> 16) & 1u);
  return (ushort)(u >> 16);
}

// ---- prep: wb[((m*32 + k/8)*256 + o)*8 + k%8] = bf16(W_m[o][k]) ----
__global__ __launch_bounds__(256) void prep_w(const float* __restrict__ w0,
                                              const float* __restrict__ w1,
                                              const float* __restrict__ w2,
                                              ushort* __restrict__ wb) {
  const int m = blockIdx.x >> 5;        // 0..55
  const int kc = blockIdx.x & 31;       // k-chunk of 8
  const int o = threadIdx.x;            // 0..255
  const float* src;
  if (m < 32)      src = w0 + ((size_t)(m * NO + o)) * NI;
  else if (m < 48) src = w1 + ((size_t)((m - 32) * NO + o)) * NI;
  else             src = w2 + ((size_t)((m - 48) * NO + o)) * NI;
  src += kc * 8;
  float4 a = *reinterpret_cast<const float4*>(src);
  float4 b = *reinterpret_cast<const float4*>(src + 4);
  u16x8 p = { f2bf(a.x), f2bf(a.y), f2bf(a.z), f2bf(a.w),
              f2bf(b.x), f2bf(b.y), f2bf(b.z), f2bf(b.w) };
  *reinterpret_cast<u16x8*>(wb + ((size_t)(blockIdx.x * 256 + o)) * 8) = p;
}

// ---- pass 1: x [1024][256 i][120 c] f32 -> xT [120 c][1024 b][256 i] bf16 ----
__global__ __launch_bounds__(256) void xpose(const float* __restrict__ x,
                                             ushort* __restrict__ xt) {
  __shared__ ushort tl[120 * 256];     // addr(c,i) = c*256 + (i ^ ((c&7)<<3)), 60 KB
  const int b = blockIdx.x;            // 1024 blocks, one b each
  const int t = threadIdx.x;
  const float* xb = x + (size_t)b * (NI * NC);
#pragma unroll
  for (int j = 0; j < 30; ++j) {       // 30*1024 = 30720 elems, f32x4 coalesced
    const int e = j * 1024 + t * 4;    // c = e%120 is a multiple of 4 -> no row wrap
    f32x4 v = *reinterpret_cast<const f32x4*>(xb + e);
    const int i = e / 120, c = e % 120;
#pragma unroll
    for (int k = 0; k < 4; ++k)
      tl[(c + k) * 256 + (i ^ (((c + k) & 7) << 3))] = f2bf(v[k]);
  }
  __syncthreads();
  ushort* dst = xt + (size_t)b * 256;
#pragma unroll
  for (int q = 0; q < 15; ++q) {       // 3840 chunks of 8 i, 15 per thread
    const int chunk = q * 256 + t;
    const int c = chunk >> 5, i0 = (chunk & 31) * 8;
    u16x8 v = *reinterpret_cast<const u16x8*>(&tl[c * 256 + (i0 ^ ((c & 7) << 3))]);
    *reinterpret_cast<u16x8*>(dst + (size_t)c * (1024 * NI) + i0) = v;
  }
}

// ---- pass 2: single-matrix-per-block GEMM. block (c, bt): [64 b] x [256 o],
// K=256 in 4 stages of 64 via global_load_lds double-buffer. No mat switching.
__global__ __launch_bounds__(256, 4) void e3mix5(const ushort* __restrict__ xt,
                                                 const ushort* __restrict__ wb,
                                                 const float* __restrict__ bias0,
                                                 float* __restrict__ out) {
  __shared__ ushort xs[2][64 * 64];    // 2 x 8 KB; row = 64 k (128 B), chunk-swizzled
  const int bid = blockIdx.x;          // 1920 = 16 bt x 120 c, c FASTEST:
  const int c  = bid % 120;            //  - out-line writers (16 c's) co-resident
  const int bt = bid / 120;            //  - W_m shared by adjacent bids
  const int m  = c < 32 ? c : (c < 80 ? 32 + (c - 32) / 3 : 48 + (c - 80) / 5);
  const int bg = bt * 64;

  const int tid = threadIdx.x, lane = tid & 63, wid = tid >> 6;
  const int rb = lane & 15, rg = lane >> 4;
  const int wo = wid * 64;             // wave's o window (4 waves x 64 o)

  // staging: lane l, instr j in {0,1} -> row = wid*16 + j*8 + (l>>3),
  // global chunk = (l&7) ^ (row&7); LDS dst = linear base + l*16 (HW rule).
  // Involution: LDS[row][q] holds global chunk q ^ (row&7).
  const int srow = wid * 16 + (lane >> 3);
  const ushort* gsrc = xt + (size_t)c * (1024 * NI) + (size_t)(bg + srow) * NI
                          + ((lane & 7) ^ (srow & 7)) * 8;
  ushort* ldst0 = &xs[0][wid * 1024];  // + j*512; wave-uniform
  ushort* ldst1 = &xs[1][wid * 1024];

  f32x4 acc[4][4];                     // [fb][fo]
#pragma unroll
  for (int i = 0; i < 4; ++i)
#pragma unroll
    for (int j = 0; j < 4; ++j) acc[i][j] = (f32x4)0.0f;

#define STAGE(LD, S)                                                          \
  do {                                                                        \
    __builtin_amdgcn_global_load_lds((const AS1 void*)(gsrc + (S) * 64),      \
                                     (AS3 void*)(LD), 16, 0, 0);              \
    __builtin_amdgcn_global_load_lds((const AS1 void*)(gsrc + (S) * 64 + 8 * NI), \
                                     (AS3 void*)((LD) + 512), 16, 0, 0);      \
  } while (0)

  STAGE(ldst0, 0);
  __syncthreads();                     // drains vmcnt(0): stage 0 ready

#pragma unroll 1
  for (int s = 0; s < 4; ++s) {
    if (s < 3) STAGE((s & 1) ? ldst0 : ldst1, s + 1);   // prefetch next stage
    const ushort* xb = xs[s & 1];
#pragma unroll
    for (int kh = 0; kh < 2; ++kh) {   // two k-halves of 32
      bf16x8 a[4], w[4];
#pragma unroll
      for (int fb = 0; fb < 4; ++fb)   // A frags: LDS, swizzled chunk
        a[fb] = *reinterpret_cast<const bf16x8*>(
            &xb[(fb * 16 + rb) * 64 + (((kh * 4 + rg) ^ (rb & 7)) * 8)]);
#pragma unroll
      for (int fo = 0; fo < 4; ++fo)   // W frags: 256B-coalesced L2 streams
        w[fo] = *reinterpret_cast<const bf16x8*>(
            wb + ((size_t)((m * 32 + s * 8 + kh * 4 + rg) * NO
                           + wo + fo * 16 + rb)) * 8);
#pragma unroll
      for (int fb = 0; fb < 4; ++fb)
#pragma unroll
        for (int fo = 0; fo < 4; ++fo)
          acc[fb][fo] = __builtin_amdgcn_mfma_f32_16x16x32_bf16(a[fb], w[fo],
                                                                acc[fb][fo], 0, 0, 0);
    }
    __syncthreads();                   // drains prefetch; protects buf reuse
  }
#undef STAGE

  if (c < 32) {                        // l=0 irreps: bias b0[c][o]
#pragma unroll
    for (int fo = 0; fo < 4; ++fo) {
      const float bv = bias0[c * NO + wo + fo * 16 + rb];
#pragma unroll
      for (int fb = 0; fb < 4; ++fb) acc[fb][fo] += bv;
    }
  }

  // scalar stores: lane's o fixed per fo; D row = rg*4 + r. L2 merges lines
  // (all 16 c-writers of a 64B line are co-resident by grid order).
#pragma unroll
  for (int fb = 0; fb < 4; ++fb) {
#pragma unroll
    for (int r = 0; r < 4; ++r) {
      const int b = bg + fb * 16 + rg * 4 + r;
      float* dst = out + ((size_t)b * NO + wo + rb) * NC + c;
#pragma unroll
      for (int fo = 0; fo < 4; ++fo)
        dst[fo * 16 * NC] = acc[fb][fo][r];
    }
  }
}

// ---- fallback (small ws): direct strided gather from x, validated in R5 ----
__global__ __launch_bounds__(512, 4) void e3mix2f(const float* __restrict__ x,
                                                  const ushort* __restrict__ wb,
                                                  const float* __restrict__ bias0,
                                                  float* __restrict__ out) {
  __shared__ ushort xs[8 * 16 * 64];
  const int bid = blockIdx.x;          // 960 = 15 ct * 64 bt
  const int ct = bid % 15, bt = bid / 15;
  const int c0 = ct * 8, bg = bt * 16;
  const int t = threadIdx.x, lane = t & 63, wid = t >> 6;
  const int sb = lane >> 2, sp = lane & 3;
  const int rb = lane & 15, rg = lane >> 4;
  const int oc = wid * 16 + rb;
  const int srow = (wid * 16 + sb) * 64;
  const int sk0 = (sp * 16) ^ ((sb & 7) << 3);
  const int sk1 = (sp * 16 + 8) ^ ((sb & 7) << 3);

  f32x4 acc[8][2];
#pragma unroll
  for (int i = 0; i < 8; ++i) { acc[i][0] = (f32x4)0.0f; acc[i][1] = (f32x4)0.0f; }
  bf16x8 w00 = {}, w01 = {}, w10 = {}, w11 = {};

#pragma unroll 1
  for (int s = 0; s < 4; ++s) {
    if (s) __syncthreads();
    u16x8 v0, v1;
    const float* src = x + (size_t)(bg + sb) * (NI * NC)
                         + (size_t)(s * 64 + sp * 16) * NC + (c0 + wid);
#pragma unroll
    for (int jj = 0; jj < 8; ++jj) v0[jj] = f2bf(src[jj * NC]);
#pragma unroll
    for (int jj = 0; jj < 8; ++jj) v1[jj] = f2bf(src[(8 + jj) * NC]);
    *reinterpret_cast<u16x8*>(&xs[srow + sk0]) = v0;
    *reinterpret_cast<u16x8*>(&xs[srow + sk1]) = v1;
    __syncthreads();

    int mprev = -1;
#pragma unroll
    for (int cc = 0; cc < 8; ++cc) {
      const int c = c0 + cc;
      const int m = c < 32 ? c : (c < 80 ? 32 + (c - 32) / 3 : 48 + (c - 80) / 5);
      if (m != mprev) {
        const ushort* wp = wb + ((size_t)((m * 32 + s * 8 + rg) * NO + oc)) * 8;
        w00 = *reinterpret_cast<const bf16x8*>(wp);
        w10 = *reinterpret_cast<const bf16x8*>(wp + (size_t)4 * NO * 8);
        w01 = *reinterpret_cast<const bf16x8*>(wp + 128 * 8);
        w11 = *reinterpret_cast<const bf16x8*>(wp + (size_t)4 * NO * 8 + 128 * 8);
        mprev = m;
      }
      const ushort* xp = xs + (cc * 16 + rb) * 64;
      const int sz = (rb & 7) << 3;
      bf16x8 a0 = *reinterpret_cast<const bf16x8*>(xp + ((rg * 8) ^ sz));
      bf16x8 a1 = *reinterpret_cast<const bf16x8*>(xp + ((32 + rg * 8) ^ sz));
      acc[cc][0] = __builtin_amdgcn_mfma_f32_16x16x32_bf16(a0, w00, acc[cc][0], 0, 0, 0);
      acc[cc][0] = __builtin_amdgcn_mfma_f32_16x16x32_bf16(a1, w10, acc[cc][0], 0, 0, 0);
      acc[cc][1] = __builtin_amdgcn_mfma_f32_16x16x32_bf16(a0, w01, acc[cc][1], 0, 0, 0);
      acc[cc][1] = __builtin_amdgcn_mfma_f32_16x16x32_bf16(a1, w11, acc[cc][1], 0, 0, 0);
    }
  }

  if (c0 < 32) {
#pragma unroll
    for (int cc = 0; cc < 8; ++cc) {
      acc[cc][0] += bias0[(c0 + cc) * NO + oc];
      acc[cc][1] += bias0[(c0 + cc) * NO + oc + 128];
    }
  }

  const int br0 = bg + rg * 4;
#pragma unroll
  for (int of = 0; of < 2; ++of)
#pragma unroll
    for (int r = 0; r < 4; ++r) {
      float4 va = make_float4(acc[0][of][r], acc[1][of][r], acc[2][of][r], acc[3][of][r]);
      float4 vb = make_float4(acc[4][of][r], acc[5][of][r], acc[6][of][r], acc[7][of][r]);
      float* dst = out + ((size_t)(br0 + r) * NO + oc + of * 128) * NC + c0;
      *reinterpret_cast<float4*>(dst) = va;
      *reinterpret_cast<float4*>(dst + 4) = vb;
    }
}

extern "C" void kernel_launch(void* const* d_in, const int* in_sizes, int n_in,
                              void* d_out, int out_size, void* d_ws, size_t ws_size,
                              hipStream_t stream) {
  const float* x  = (const float*)d_in[0];
  const float* w0 = (const float*)d_in[1];
  const float* w1 = (const float*)d_in[2];
  const float* w2 = (const float*)d_in[3];
  const float* b0 = (const float*)d_in[4];
  float* out = (float*)d_out;
  ushort* wb = (ushort*)d_ws;                       // 7.34 MB
  ushort* xt = wb + WELEMS;                         // +62.9 MB

  prep_w<<<56 * 32, 256, 0, stream>>>(w0, w1, w2, wb);
  const bool big = ws_size >= (size_t)2 * (WELEMS + XT_ELEMS);
  if (big) {
    xpose<<<1024, 256, 0, stream>>>(x, xt);
    e3mix5<<<16 * 120, 256, 0, stream>>>(xt, wb, b0, out);
  } else {
    e3mix2f<<<960, 512, 0, stream>>>(x, wb, b0, out);
  }
}

// Round 9
// 139.823 us; speedup vs baseline: 2.7731x; 2.7731x over previous
//
#include <hip/hip_runtime.h>

typedef __attribute__((ext_vector_type(8))) short bf16x8;
typedef __attribute__((ext_vector_type(4))) float f32x4;
typedef __attribute__((ext_vector_type(8))) unsigned short u16x8;

#define DEVINL __device__ __forceinline__
#define AS1 __attribute__((address_space(1)))
#define AS3 __attribute__((address_space(3)))

constexpr int NI = 256;   // input channels (K)
constexpr int NO = 256;   // output channels
constexpr int NC = 120;   // irrep feature width
constexpr int WELEMS = 56 * NO * NI;                 // 3,670,016
constexpr size_t XT_ELEMS = (size_t)NC * 1024 * NI;  // 31,457,280

DEVINL ushort f2bf(float x) {   // round-to-nearest-even fp32 -> bf16 bits
  unsigned u = __float_as_uint(x);
  u += 0x7FFFu + ((u >> 16) & 1u);
  return (ushort)(u >> 16);
}

// ---- prep: wb[((m*32 + k/8)*256 + o)*8 + k%8] = bf16(W_m[o][k]) ----
__global__ __launch_bounds__(256) void prep_w(const float* __restrict__ w0,
                                              const float* __restrict__ w1,
                                              const float* __restrict__ w2,
                                              ushort* __restrict__ wb) {
  const int m = blockIdx.x >> 5;        // 0..55
  const int kc = blockIdx.x & 31;       // k-chunk of 8
  const int o = threadIdx.x;            // 0..255
  const float* src;
  if (m < 32)      src = w0 + ((size_t)(m * NO + o)) * NI;
  else if (m < 48) src = w1 + ((size_t)((m - 32) * NO + o)) * NI;
  else             src = w2 + ((size_t)((m - 48) * NO + o)) * NI;
  src += kc * 8;
  float4 a = *reinterpret_cast<const float4*>(src);
  float4 b = *reinterpret_cast<const float4*>(src + 4);
  u16x8 p = { f2bf(a.x), f2bf(a.y), f2bf(a.z), f2bf(a.w),
              f2bf(b.x), f2bf(b.y), f2bf(b.z), f2bf(b.w) };
  *reinterpret_cast<u16x8*>(wb + ((size_t)(blockIdx.x * 256 + o)) * 8) = p;
}

// ---- pass 1: x [1024][256 i][120 c] f32 -> xT [120 c][1024 b][256 i] bf16 ----
__global__ __launch_bounds__(256) void xpose(const float* __restrict__ x,
                                             ushort* __restrict__ xt) {
  __shared__ ushort tl[120 * 256];     // addr(c,i) = c*256 + (i ^ ((c&7)<<3)), 60 KB
  const int b = blockIdx.x;            // 1024 blocks, one b each
  const int t = threadIdx.x;
  const float* xb = x + (size_t)b * (NI * NC);
#pragma unroll
  for (int j = 0; j < 30; ++j) {       // 30*1024 = 30720 elems, f32x4 coalesced
    const int e = j * 1024 + t * 4;    // c = e%120 is a multiple of 4 -> no row wrap
    f32x4 v = *reinterpret_cast<const f32x4*>(xb + e);
    const int i = e / 120, c = e % 120;
#pragma unroll
    for (int k = 0; k < 4; ++k)
      tl[(c + k) * 256 + (i ^ (((c + k) & 7) << 3))] = f2bf(v[k]);
  }
  __syncthreads();
  ushort* dst = xt + (size_t)b * 256;
#pragma unroll
  for (int q = 0; q < 15; ++q) {       // 3840 chunks of 8 i, 15 per thread
    const int chunk = q * 256 + t;
    const int c = chunk >> 5, i0 = (chunk & 31) * 8;
    u16x8 v = *reinterpret_cast<const u16x8*>(&tl[c * 256 + (i0 ^ ((c & 7) << 3))]);
    *reinterpret_cast<u16x8*>(dst + (size_t)c * (1024 * NI) + i0) = v;
  }
}

// ---- pass 2: single-matrix-per-block GEMM (R8 core, FETCH-proven clean).
// block (c, bt): [64 b] x [256 o] x [1 c]; K=256, 4 stages via global_load_lds.
// Epilogue: bf16 results IN-PLACE into xt[c][b][o] (exactly the region this
// block read; all loads drained at last barrier -> no hazard). 32B-run stores.
__global__ __launch_bounds__(256, 4) void e3mix6(ushort* xt,
                                                 const ushort* __restrict__ wb,
                                                 const float* __restrict__ bias0) {
  __shared__ ushort xs[2][64 * 64];    // 2 x 8 KB; row = 64 k (128 B), chunk-swizzled
  const int bid = blockIdx.x;          // 1920 = 16 bt x 120 c, c FASTEST
  const int c  = bid % 120;            //  (bid%8 == c%8 -> W_m pinned per XCD)
  const int bt = bid / 120;
  const int m  = c < 32 ? c : (c < 80 ? 32 + (c - 32) / 3 : 48 + (c - 80) / 5);
  const int bg = bt * 64;

  const int tid = threadIdx.x, lane = tid & 63, wid = tid >> 6;
  const int rb = lane & 15, rg = lane >> 4;
  const int wo = wid * 64;             // wave's o window (4 waves x 64 o)

  // staging: lane l, instr j in {0,1} -> row = wid*16 + j*8 + (l>>3),
  // global chunk = (l&7) ^ (row&7); LDS dst linear (HW rule).
  const int srow = wid * 16 + (lane >> 3);
  const ushort* gsrc = xt + (size_t)c * (1024 * NI) + (size_t)(bg + srow) * NI
                          + ((lane & 7) ^ (srow & 7)) * 8;
  ushort* ldst0 = &xs[0][wid * 1024];
  ushort* ldst1 = &xs[1][wid * 1024];

  f32x4 acc[4][4];                     // [fb][fo]
#pragma unroll
  for (int i = 0; i < 4; ++i)
#pragma unroll
    for (int j = 0; j < 4; ++j) acc[i][j] = (f32x4)0.0f;

#define STAGE(LD, S)                                                          \
  do {                                                                        \
    __builtin_amdgcn_global_load_lds((const AS1 void*)(gsrc + (S) * 64),      \
                                     (AS3 void*)(LD), 16, 0, 0);              \
    __builtin_amdgcn_global_load_lds((const AS1 void*)(gsrc + (S) * 64 + 8 * NI), \
                                     (AS3 void*)((LD) + 512), 16, 0, 0);      \
  } while (0)

  STAGE(ldst0, 0);
  __syncthreads();                     // drains vmcnt: stage 0 ready

#pragma unroll 1
  for (int s = 0; s < 4; ++s) {
    if (s < 3) STAGE((s & 1) ? ldst0 : ldst1, s + 1);   // prefetch next stage
    const ushort* xb = xs[s & 1];
#pragma unroll
    for (int kh = 0; kh < 2; ++kh) {   // two k-halves of 32
      bf16x8 a[4], w[4];
#pragma unroll
      for (int fb = 0; fb < 4; ++fb)   // A frags: LDS, swizzled chunk
        a[fb] = *reinterpret_cast<const bf16x8*>(
            &xb[(fb * 16 + rb) * 64 + (((kh * 4 + rg) ^ (rb & 7)) * 8)]);
#pragma unroll
      for (int fo = 0; fo < 4; ++fo)   // W frags: 256B-coalesced L2 streams
        w[fo] = *reinterpret_cast<const bf16x8*>(
            wb + ((size_t)((m * 32 + s * 8 + kh * 4 + rg) * NO
                           + wo + fo * 16 + rb)) * 8);
#pragma unroll
      for (int fb = 0; fb < 4; ++fb)
#pragma unroll
        for (int fo = 0; fo < 4; ++fo)
          acc[fb][fo] = __builtin_amdgcn_mfma_f32_16x16x32_bf16(a[fb], w[fo],
                                                                acc[fb][fo], 0, 0, 0);
    }
    __syncthreads();                   // drains prefetch; protects buf reuse
  }
#undef STAGE

  if (c < 32) {                        // l=0 irreps: bias b0[c][o]
#pragma unroll
    for (int fo = 0; fo < 4; ++fo) {
      const float bv = bias0[c * NO + wo + fo * 16 + rb];
#pragma unroll
      for (int fb = 0; fb < 4; ++fb) acc[fb][fo] += bv;
    }
  }

  // in-place bf16 store: per instr, 16-lane runs of 32B (4 runs) -> no
  // write amplification (R5-proven store class).
  ushort* ot = xt + (size_t)c * (1024 * NI);
#pragma unroll
  for (int fb = 0; fb < 4; ++fb)
#pragma unroll
    for (int r = 0; r < 4; ++r) {
      const size_t brow = (size_t)(bg + fb * 16 + rg * 4 + r) * NO;
#pragma unroll
      for (int fo = 0; fo < 4; ++fo)
        ot[brow + wo + fo * 16 + rb] = f2bf(acc[fb][fo][r]);
    }
}

// ---- pass 3: outT=xt [120 c][1024 b][256 o] bf16 -> out [1024 b][256 o][120 c] f32
__global__ __launch_bounds__(256) void otrans(const ushort* __restrict__ xt,
                                              float* __restrict__ out) {
  __shared__ ushort tl[120 * 258];     // row stride 258 u16 = 129 words (odd) -> c-walk conflict-free
  const int b = blockIdx.x;            // 1024 blocks, one b each
  const int t = threadIdx.x;
  const int lane32 = t & 31, rowg = t >> 3 >> 2;  // rowg = t >> 5
  const ushort* src = xt + (size_t)b * NO;
#pragma unroll
  for (int j = 0; j < 15; ++j) {       // 120 rows, 8 per iter; 512B contiguous reads
    const int c = j * 8 + rowg;
    u16x8 v = *reinterpret_cast<const u16x8*>(
        src + (size_t)c * (1024 * NI) + lane32 * 8);
    *reinterpret_cast<u16x8*>(&tl[c * 258 + lane32 * 8]) = v;
  }
  __syncthreads();
  float* dst = out + ((size_t)b * NO + t) * NC;   // thread t owns o = t: 480B row
#pragma unroll
  for (int j = 0; j < 30; ++j) {
    float4 v;
    v.x = __uint_as_float((unsigned)tl[(4 * j + 0) * 258 + t] << 16);
    v.y = __uint_as_float((unsigned)tl[(4 * j + 1) * 258 + t] << 16);
    v.z = __uint_as_float((unsigned)tl[(4 * j + 2) * 258 + t] << 16);
    v.w = __uint_as_float((unsigned)tl[(4 * j + 3) * 258 + t] << 16);
    *reinterpret_cast<float4*>(dst + 4 * j) = v;
  }
}

// ---- fallback (small ws): direct strided gather from x, validated in R5 ----
__global__ __launch_bounds__(512, 4) void e3mix2f(const float* __restrict__ x,
                                                  const ushort* __restrict__ wb,
                                                  const float* __restrict__ bias0,
                                                  float* __restrict__ out) {
  __shared__ ushort xs[8 * 16 * 64];
  const int bid = blockIdx.x;          // 960 = 15 ct * 64 bt
  const int ct = bid % 15, bt = bid / 15;
  const int c0 = ct * 8, bg = bt * 16;
  const int t = threadIdx.x, lane = t & 63, wid = t >> 6;
  const int sb = lane >> 2, sp = lane & 3;
  const int rb = lane & 15, rg = lane >> 4;
  const int oc = wid * 16 + rb;
  const int srow = (wid * 16 + sb) * 64;
  const int sk0 = (sp * 16) ^ ((sb & 7) << 3);
  const int sk1 = (sp * 16 + 8) ^ ((sb & 7) << 3);

  f32x4 acc[8][2];
#pragma unroll
  for (int i = 0; i < 8; ++i) { acc[i][0] = (f32x4)0.0f; acc[i][1] = (f32x4)0.0f; }
  bf16x8 w00 = {}, w01 = {}, w10 = {}, w11 = {};

#pragma unroll 1
  for (int s = 0; s < 4; ++s) {
    if (s) __syncthreads();
    u16x8 v0, v1;
    const float* src = x + (size_t)(bg + sb) * (NI * NC)
                         + (size_t)(s * 64 + sp * 16) * NC + (c0 + wid);
#pragma unroll
    for (int jj = 0; jj < 8; ++jj) v0[jj] = f2bf(src[jj * NC]);
#pragma unroll
    for (int jj = 0; jj < 8; ++jj) v1[jj] = f2bf(src[(8 + jj) * NC]);
    *reinterpret_cast<u16x8*>(&xs[srow + sk0]) = v0;
    *reinterpret_cast<u16x8*>(&xs[srow + sk1]) = v1;
    __syncthreads();

    int mprev = -1;
#pragma unroll
    for (int cc = 0; cc < 8; ++cc) {
      const int c = c0 + cc;
      const int m = c < 32 ? c : (c < 80 ? 32 + (c - 32) / 3 : 48 + (c - 80) / 5);
      if (m != mprev) {
        const ushort* wp = wb + ((size_t)((m * 32 + s * 8 + rg) * NO + oc)) * 8;
        w00 = *reinterpret_cast<const bf16x8*>(wp);
        w10 = *reinterpret_cast<const bf16x8*>(wp + (size_t)4 * NO * 8);
        w01 = *reinterpret_cast<const bf16x8*>(wp + 128 * 8);
        w11 = *reinterpret_cast<const bf16x8*>(wp + (size_t)4 * NO * 8 + 128 * 8);
        mprev = m;
      }
      const ushort* xp = xs + (cc * 16 + rb) * 64;
      const int sz = (rb & 7) << 3;
      bf16x8 a0 = *reinterpret_cast<const bf16x8*>(xp + ((rg * 8) ^ sz));
      bf16x8 a1 = *reinterpret_cast<const bf16x8*>(xp + ((32 + rg * 8) ^ sz));
      acc[cc][0] = __builtin_amdgcn_mfma_f32_16x16x32_bf16(a0, w00, acc[cc][0], 0, 0, 0);
      acc[cc][0] = __builtin_amdgcn_mfma_f32_16x16x32_bf16(a1, w10, acc[cc][0], 0, 0, 0);
      acc[cc][1] = __builtin_amdgcn_mfma_f32_16x16x32_bf16(a0, w01, acc[cc][1], 0, 0, 0);
      acc[cc][1] = __builtin_amdgcn_mfma_f32_16x16x32_bf16(a1, w11, acc[cc][1], 0, 0, 0);
    }
  }

  if (c0 < 32) {
#pragma unroll
    for (int cc = 0; cc < 8; ++cc) {
      acc[cc][0] += bias0[(c0 + cc) * NO + oc];
      acc[cc][1] += bias0[(c0 + cc) * NO + oc + 128];
    }
  }

  const int br0 = bg + rg * 4;
#pragma unroll
  for (int of = 0; of < 2; ++of)
#pragma unroll
    for (int r = 0; r < 4; ++r) {
      float4 va = make_float4(acc[0][of][r], acc[1][of][r], acc[2][of][r], acc[3][of][r]);
      float4 vb = make_float4(acc[4][of][r], acc[5][of][r], acc[6][of][r], acc[7][of][r]);
      float* dst = out + ((size_t)(br0 + r) * NO + oc + of * 128) * NC + c0;
      *reinterpret_cast<float4*>(dst) = va;
      *reinterpret_cast<float4*>(dst + 4) = vb;
    }
}

extern "C" void kernel_launch(void* const* d_in, const int* in_sizes, int n_in,
                              void* d_out, int out_size, void* d_ws, size_t ws_size,
                              hipStream_t stream) {
  const float* x  = (const float*)d_in[0];
  const float* w0 = (const float*)d_in[1];
  const float* w1 = (const float*)d_in[2];
  const float* w2 = (const float*)d_in[3];
  const float* b0 = (const float*)d_in[4];
  float* out = (float*)d_out;
  ushort* wb = (ushort*)d_ws;                       // 7.34 MB
  ushort* xt = wb + WELEMS;                         // +62.9 MB (xT, then outT in-place)

  prep_w<<<56 * 32, 256, 0, stream>>>(w0, w1, w2, wb);
  const bool big = ws_size >= (size_t)2 * (WELEMS + XT_ELEMS);
  if (big) {
    xpose<<<1024, 256, 0, stream>>>(x, xt);
    e3mix6<<<16 * 120, 256, 0, stream>>>(xt, wb, b0);
    otrans<<<1024, 256, 0, stream>>>(xt, out);
  } else {
    e3mix2f<<<960, 512, 0, stream>>>(x, wb, b0, out);
  }
}

// Round 10
// 136.796 us; speedup vs baseline: 2.8345x; 1.0221x over previous
//
#include <hip/hip_runtime.h>

typedef __attribute__((ext_vector_type(8))) short bf16x8;
typedef __attribute__((ext_vector_type(4))) float f32x4;
typedef __attribute__((ext_vector_type(8))) unsigned short u16x8;

#define DEVINL __device__ __forceinline__
#define AS1 __attribute__((address_space(1)))
#define AS3 __attribute__((address_space(3)))

constexpr int NI = 256;   // input channels (K)
constexpr int NO = 256;   // output channels
constexpr int NC = 120;   // irrep feature width
constexpr int WELEMS = 56 * NO * NI;                 // 3,670,016
constexpr size_t XT_ELEMS = (size_t)NC * 1024 * NI;  // 31,457,280

DEVINL ushort f2bf(float x) {   // round-to-nearest-even fp32 -> bf16 bits
  unsigned u = __float_as_uint(x);
  u += 0x7FFFu + ((u >> 16) & 1u);
  return (ushort)(u >> 16);
}
DEVINL float bf2f(ushort v) { return __uint_as_float((unsigned)v << 16); }

// ---- prep: wb[((m*32 + k/8)*256 + o)*8 + k%8] = bf16(W_m[o][k]) ----
__global__ __launch_bounds__(256) void prep_w(const float* __restrict__ w0,
                                              const float* __restrict__ w1,
                                              const float* __restrict__ w2,
                                              ushort* __restrict__ wb) {
  const int m = blockIdx.x >> 5;        // 0..55
  const int kc = blockIdx.x & 31;       // k-chunk of 8
  const int o = threadIdx.x;            // 0..255
  const float* src;
  if (m < 32)      src = w0 + ((size_t)(m * NO + o)) * NI;
  else if (m < 48) src = w1 + ((size_t)((m - 32) * NO + o)) * NI;
  else             src = w2 + ((size_t)((m - 48) * NO + o)) * NI;
  src += kc * 8;
  float4 a = *reinterpret_cast<const float4*>(src);
  float4 b = *reinterpret_cast<const float4*>(src + 4);
  u16x8 p = { f2bf(a.x), f2bf(a.y), f2bf(a.z), f2bf(a.w),
              f2bf(b.x), f2bf(b.y), f2bf(b.z), f2bf(b.w) };
  *reinterpret_cast<u16x8*>(wb + ((size_t)(blockIdx.x * 256 + o)) * 8) = p;
}

// ---- pass 1: x [1024][256 i][120 c] f32 -> xT [120 c][1024 b][256 i] bf16 ----
// v2: 2 i-halves per b (grid 2048, 30.7 KB LDS -> 5 blocks/CU) and bank-safe
// swizzle i ^ (((c>>2)&31)<<2): write-phase lanes vary c (step 4) at fixed i
// -> 16-way bank spread (was 2 -> ~15-way conflict). Read-back u16x4 intact.
__global__ __launch_bounds__(256) void xpose(const float* __restrict__ x,
                                             ushort* __restrict__ xt) {
  __shared__ ushort tl[120 * 128];     // addr(c,i) = c*128 + (i ^ swz(c))
  const int bid = blockIdx.x;          // 2048 = b*2 + ih
  const int b = bid >> 1, ih = bid & 1;
  const int t = threadIdx.x;
  const float* xb = x + (size_t)b * (NI * NC) + (size_t)ih * 128 * NC;
#pragma unroll
  for (int j = 0; j < 15; ++j) {       // 15360 elems, f32x4 coalesced reads
    const int e = j * 1024 + t * 4;    // c = e%120 multiple of 4 -> no row wrap
    f32x4 v = *reinterpret_cast<const f32x4*>(xb + e);
    const int i = e / 120, c = e % 120;
#pragma unroll
    for (int k = 0; k < 4; ++k)
      tl[(c + k) * 128 + (i ^ ((((c + k) >> 2) & 31) << 2))] = f2bf(v[k]);
  }
  __syncthreads();
  ushort* dst = xt + (size_t)b * NI + ih * 128;
#pragma unroll
  for (int q = 0; q < 15; ++q) {       // 3840 u16x4 chunks; 256B runs per c-row
    const int chunk = q * 256 + t;
    const int c = chunk >> 5, i0 = (chunk & 31) * 4;
    ushort4 v = *reinterpret_cast<const ushort4*>(
        &tl[c * 128 + (i0 ^ (((c >> 2) & 31) << 2))]);
    *reinterpret_cast<ushort4*>(dst + (size_t)c * (1024 * NI) + i0) = v;
  }
}

// ---- pass 2: single-matrix-per-block GEMM (R8/R9 core, proven clean).
// block (c, bt): [64 b] x [256 o] x [1 c]; K=256, 4 stages via global_load_lds.
// Epilogue: bf16 results IN-PLACE into xt[c][b][o] (exact region this block
// read; all loads drained at last barrier). 32B-run stores.
__global__ __launch_bounds__(256, 4) void e3mix6(ushort* xt,
                                                 const ushort* __restrict__ wb,
                                                 const float* __restrict__ bias0) {
  __shared__ ushort xs[2][64 * 64];    // 2 x 8 KB; row = 64 k (128 B), chunk-swizzled
  const int bid = blockIdx.x;          // 1920 = 16 bt x 120 c, c FASTEST
  const int c  = bid % 120;            //  (bid%8 == c%8 -> W_m pinned per XCD)
  const int bt = bid / 120;
  const int m  = c < 32 ? c : (c < 80 ? 32 + (c - 32) / 3 : 48 + (c - 80) / 5);
  const int bg = bt * 64;

  const int tid = threadIdx.x, lane = tid & 63, wid = tid >> 6;
  const int rb = lane & 15, rg = lane >> 4;
  const int wo = wid * 64;             // wave's o window (4 waves x 64 o)

  // staging: lane l, instr j in {0,1} -> row = wid*16 + j*8 + (l>>3),
  // global chunk = (l&7) ^ (row&7); LDS dst linear (HW rule).
  const int srow = wid * 16 + (lane >> 3);
  const ushort* gsrc = xt + (size_t)c * (1024 * NI) + (size_t)(bg + srow) * NI
                          + ((lane & 7) ^ (srow & 7)) * 8;
  ushort* ldst0 = &xs[0][wid * 1024];
  ushort* ldst1 = &xs[1][wid * 1024];

  f32x4 acc[4][4];                     // [fb][fo]
#pragma unroll
  for (int i = 0; i < 4; ++i)
#pragma unroll
    for (int j = 0; j < 4; ++j) acc[i][j] = (f32x4)0.0f;

#define STAGE(LD, S)                                                          \
  do {                                                                        \
    __builtin_amdgcn_global_load_lds((const AS1 void*)(gsrc + (S) * 64),      \
                                     (AS3 void*)(LD), 16, 0, 0);              \
    __builtin_amdgcn_global_load_lds((const AS1 void*)(gsrc + (S) * 64 + 8 * NI), \
                                     (AS3 void*)((LD) + 512), 16, 0, 0);      \
  } while (0)

  STAGE(ldst0, 0);
  __syncthreads();                     // drains vmcnt: stage 0 ready

#pragma unroll 1
  for (int s = 0; s < 4; ++s) {
    if (s < 3) STAGE((s & 1) ? ldst0 : ldst1, s + 1);   // prefetch next stage
    const ushort* xb = xs[s & 1];
#pragma unroll
    for (int kh = 0; kh < 2; ++kh) {   // two k-halves of 32
      bf16x8 a[4], w[4];
#pragma unroll
      for (int fb = 0; fb < 4; ++fb)   // A frags: LDS, swizzled chunk
        a[fb] = *reinterpret_cast<const bf16x8*>(
            &xb[(fb * 16 + rb) * 64 + (((kh * 4 + rg) ^ (rb & 7)) * 8)]);
#pragma unroll
      for (int fo = 0; fo < 4; ++fo)   // W frags: 256B-coalesced L2 streams
        w[fo] = *reinterpret_cast<const bf16x8*>(
            wb + ((size_t)((m * 32 + s * 8 + kh * 4 + rg) * NO
                           + wo + fo * 16 + rb)) * 8);
#pragma unroll
      for (int fb = 0; fb < 4; ++fb)
#pragma unroll
        for (int fo = 0; fo < 4; ++fo)
          acc[fb][fo] = __builtin_amdgcn_mfma_f32_16x16x32_bf16(a[fb], w[fo],
                                                                acc[fb][fo], 0, 0, 0);
    }
    __syncthreads();                   // drains prefetch; protects buf reuse
  }
#undef STAGE

  if (c < 32) {                        // l=0 irreps: bias b0[c][o]
#pragma unroll
    for (int fo = 0; fo < 4; ++fo) {
      const float bv = bias0[c * NO + wo + fo * 16 + rb];
#pragma unroll
      for (int fb = 0; fb < 4; ++fb) acc[fb][fo] += bv;
    }
  }

  ushort* ot = xt + (size_t)c * (1024 * NI);
#pragma unroll
  for (int fb = 0; fb < 4; ++fb)
#pragma unroll
    for (int r = 0; r < 4; ++r) {
      const size_t brow = (size_t)(bg + fb * 16 + rg * 4 + r) * NO;
#pragma unroll
      for (int fo = 0; fo < 4; ++fo)
        ot[brow + wo + fo * 16 + rb] = f2bf(acc[fb][fo][r]);
    }
}

// ---- pass 3: outT=xt [120 c][1024 b][256 o] bf16 -> out [1024 b][256 o][120 c] f32
// v2: 2 o-halves per b (grid 2048, 31.7 KB LDS -> 5 blocks/CU).
__global__ __launch_bounds__(256) void otrans(const ushort* __restrict__ xt,
                                              float* __restrict__ out) {
  __shared__ ushort tl[120 * 132];     // row stride 132 u16 (264 B, padded)
  const int bid = blockIdx.x;          // 2048 = b*2 + oh
  const int b = bid >> 1, oh = bid & 1;
  const int t = threadIdx.x;
  const ushort* src = xt + (size_t)b * NO + oh * 128;
#pragma unroll
  for (int q = 0; q < 15; ++q) {       // 3840 u16x4 chunks; 256B contiguous reads
    const int chunk = q * 256 + t;
    const int c = chunk >> 5, i0 = (chunk & 31) * 4;
    ushort4 v = *reinterpret_cast<const ushort4*>(
        src + (size_t)c * (1024 * NI) + i0);
    *reinterpret_cast<ushort4*>(&tl[c * 132 + i0]) = v;
  }
  __syncthreads();
  const int op = t & 127, ch = t >> 7; // thread: o = oh*128+op, c-half ch
  float* dst = out + ((size_t)b * NO + oh * 128 + op) * NC + ch * 60;
#pragma unroll
  for (int j = 0; j < 15; ++j) {       // 60 c per thread: 240B contiguous run
    float4 v;
    v.x = bf2f(tl[(ch * 60 + 4 * j + 0) * 132 + op]);
    v.y = bf2f(tl[(ch * 60 + 4 * j + 1) * 132 + op]);
    v.z = bf2f(tl[(ch * 60 + 4 * j + 2) * 132 + op]);
    v.w = bf2f(tl[(ch * 60 + 4 * j + 3) * 132 + op]);
    *reinterpret_cast<float4*>(dst + 4 * j) = v;
  }
}

// ---- fallback (small ws): direct strided gather from x, validated in R5 ----
__global__ __launch_bounds__(512, 4) void e3mix2f(const float* __restrict__ x,
                                                  const ushort* __restrict__ wb,
                                                  const float* __restrict__ bias0,
                                                  float* __restrict__ out) {
  __shared__ ushort xs[8 * 16 * 64];
  const int bid = blockIdx.x;          // 960 = 15 ct * 64 bt
  const int ct = bid % 15, bt = bid / 15;
  const int c0 = ct * 8, bg = bt * 16;
  const int t = threadIdx.x, lane = t & 63, wid = t >> 6;
  const int sb = lane >> 2, sp = lane & 3;
  const int rb = lane & 15, rg = lane >> 4;
  const int oc = wid * 16 + rb;
  const int srow = (wid * 16 + sb) * 64;
  const int sk0 = (sp * 16) ^ ((sb & 7) << 3);
  const int sk1 = (sp * 16 + 8) ^ ((sb & 7) << 3);

  f32x4 acc[8][2];
#pragma unroll
  for (int i = 0; i < 8; ++i) { acc[i][0] = (f32x4)0.0f; acc[i][1] = (f32x4)0.0f; }
  bf16x8 w00 = {}, w01 = {}, w10 = {}, w11 = {};

#pragma unroll 1
  for (int s = 0; s < 4; ++s) {
    if (s) __syncthreads();
    u16x8 v0, v1;
    const float* src = x + (size_t)(bg + sb) * (NI * NC)
                         + (size_t)(s * 64 + sp * 16) * NC + (c0 + wid);
#pragma unroll
    for (int jj = 0; jj < 8; ++jj) v0[jj] = f2bf(src[jj * NC]);
#pragma unroll
    for (int jj = 0; jj < 8; ++jj) v1[jj] = f2bf(src[(8 + jj) * NC]);
    *reinterpret_cast<u16x8*>(&xs[srow + sk0]) = v0;
    *reinterpret_cast<u16x8*>(&xs[srow + sk1]) = v1;
    __syncthreads();

    int mprev = -1;
#pragma unroll
    for (int cc = 0; cc < 8; ++cc) {
      const int c = c0 + cc;
      const int m = c < 32 ? c : (c < 80 ? 32 + (c - 32) / 3 : 48 + (c - 80) / 5);
      if (m != mprev) {
        const ushort* wp = wb + ((size_t)((m * 32 + s * 8 + rg) * NO + oc)) * 8;
        w00 = *reinterpret_cast<const bf16x8*>(wp);
        w10 = *reinterpret_cast<const bf16x8*>(wp + (size_t)4 * NO * 8);
        w01 = *reinterpret_cast<const bf16x8*>(wp + 128 * 8);
        w11 = *reinterpret_cast<const bf16x8*>(wp + (size_t)4 * NO * 8 + 128 * 8);
        mprev = m;
      }
      const ushort* xp = xs + (cc * 16 + rb) * 64;
      const int sz = (rb & 7) << 3;
      bf16x8 a0 = *reinterpret_cast<const bf16x8*>(xp + ((rg * 8) ^ sz));
      bf16x8 a1 = *reinterpret_cast<const bf16x8*>(xp + ((32 + rg * 8) ^ sz));
      acc[cc][0] = __builtin_amdgcn_mfma_f32_16x16x32_bf16(a0, w00, acc[cc][0], 0, 0, 0);
      acc[cc][0] = __builtin_amdgcn_mfma_f32_16x16x32_bf16(a1, w10, acc[cc][0], 0, 0, 0);
      acc[cc][1] = __builtin_amdgcn_mfma_f32_16x16x32_bf16(a0, w01, acc[cc][1], 0, 0, 0);
      acc[cc][1] = __builtin_amdgcn_mfma_f32_16x16x32_bf16(a1, w11, acc[cc][1], 0, 0, 0);
    }
  }

  if (c0 < 32) {
#pragma unroll
    for (int cc = 0; cc < 8; ++cc) {
      acc[cc][0] += bias0[(c0 + cc) * NO + oc];
      acc[cc][1] += bias0[(c0 + cc) * NO + oc + 128];
    }
  }

  const int br0 = bg + rg * 4;
#pragma unroll
  for (int of = 0; of < 2; ++of)
#pragma unroll
    for (int r = 0; r < 4; ++r) {
      float4 va = make_float4(acc[0][of][r], acc[1][of][r], acc[2][of][r], acc[3][of][r]);
      float4 vb = make_float4(acc[4][of][r], acc[5][of][r], acc[6][of][r], acc[7][of][r]);
      float* dst = out + ((size_t)(br0 + r) * NO + oc + of * 128) * NC + c0;
      *reinterpret_cast<float4*>(dst) = va;
      *reinterpret_cast<float4*>(dst + 4) = vb;
    }
}

extern "C" void kernel_launch(void* const* d_in, const int* in_sizes, int n_in,
                              void* d_out, int out_size, void* d_ws, size_t ws_size,
                              hipStream_t stream) {
  const float* x  = (const float*)d_in[0];
  const float* w0 = (const float*)d_in[1];
  const float* w1 = (const float*)d_in[2];
  const float* w2 = (const float*)d_in[3];
  const float* b0 = (const float*)d_in[4];
  float* out = (float*)d_out;
  ushort* wb = (ushort*)d_ws;                       // 7.34 MB
  ushort* xt = wb + WELEMS;                         // +62.9 MB (xT, then outT in-place)

  prep_w<<<56 * 32, 256, 0, stream>>>(w0, w1, w2, wb);
  const bool big = ws_size >= (size_t)2 * (WELEMS + XT_ELEMS);
  if (big) {
    xpose<<<2048, 256, 0, stream>>>(x, xt);
    e3mix6<<<16 * 120, 256, 0, stream>>>(xt, wb, b0);
    otrans<<<2048, 256, 0, stream>>>(xt, out);
  } else {
    e3mix2f<<<960, 512, 0, stream>>>(x, wb, b0, out);
  }
}

// Round 11
// 132.235 us; speedup vs baseline: 2.9323x; 1.0345x over previous
//
#include <hip/hip_runtime.h>

typedef __attribute__((ext_vector_type(8))) short bf16x8;
typedef __attribute__((ext_vector_type(4))) float f32x4;
typedef __attribute__((ext_vector_type(8))) unsigned short u16x8;

#define DEVINL __device__ __forceinline__
#define AS1 __attribute__((address_space(1)))
#define AS3 __attribute__((address_space(3)))

constexpr int NI = 256;   // input channels (K)
constexpr int NO = 256;   // output channels
constexpr int NC = 120;   // irrep feature width
constexpr int BROW = NC * NI;                        // 30720: one b-row of xt
constexpr int WELEMS = 56 * NO * NI;                 // 3,670,016
constexpr size_t XT_ELEMS = (size_t)NC * 1024 * NI;  // 31,457,280

DEVINL ushort f2bf(float x) {   // round-to-nearest-even fp32 -> bf16 bits
  unsigned u = __float_as_uint(x);
  u += 0x7FFFu + ((u >> 16) & 1u);
  return (ushort)(u >> 16);
}
DEVINL float bf2f(ushort v) { return __uint_as_float((unsigned)v << 16); }

// ---- prep: wb[((m*32 + k/8)*256 + o)*8 + k%8] = bf16(W_m[o][k]) ----
__global__ __launch_bounds__(256) void prep_w(const float* __restrict__ w0,
                                              const float* __restrict__ w1,
                                              const float* __restrict__ w2,
                                              ushort* __restrict__ wb) {
  const int m = blockIdx.x >> 5;        // 0..55
  const int kc = blockIdx.x & 31;       // k-chunk of 8
  const int o = threadIdx.x;            // 0..255
  const float* src;
  if (m < 32)      src = w0 + ((size_t)(m * NO + o)) * NI;
  else if (m < 48) src = w1 + ((size_t)((m - 32) * NO + o)) * NI;
  else             src = w2 + ((size_t)((m - 48) * NO + o)) * NI;
  src += kc * 8;
  float4 a = *reinterpret_cast<const float4*>(src);
  float4 b = *reinterpret_cast<const float4*>(src + 4);
  u16x8 p = { f2bf(a.x), f2bf(a.y), f2bf(a.z), f2bf(a.w),
              f2bf(b.x), f2bf(b.y), f2bf(b.z), f2bf(b.w) };
  *reinterpret_cast<u16x8*>(wb + ((size_t)(blockIdx.x * 256 + o)) * 8) = p;
}

// ---- pass 1: x [1024 b][256 i][120 c] f32 -> xt [1024 b][120 c][256 i] bf16 ----
// v3: b-major target. Block (b, iq) handles 64 i x 120 c: global reads 30 KB
// contiguous, global writes 128B runs into xt[b] (61 KB/b contiguous overall).
// LDS: f32 natural [i][c], stride 121 -> scalar writes free (bank 25i+c),
// column reads conflict-free per instr ({0,8,16,24} xor c covers 32 banks).
__global__ __launch_bounds__(256) void xpose(const float* __restrict__ x,
                                             ushort* __restrict__ xt) {
  __shared__ float tl[64 * 121];       // 31 KB -> 5 blocks/CU
  const int bid = blockIdx.x;          // 4096 = b*4 + iq
  const int b = bid >> 2, iq = bid & 3;
  const int t = threadIdx.x;
  const float* xb = x + (size_t)b * BROW + (size_t)iq * 64 * NC;
#pragma unroll
  for (int j = 0; j < 15; ++j) {       // 7680 f32, float2 coalesced reads
    const int e = (j * 256 + t) * 2;   // even -> c even, no row wrap (c<=118)
    float2 v = *reinterpret_cast<const float2*>(xb + e);
    const int i = e / 120, c = e % 120;
    tl[i * 121 + c] = v.x;
    tl[i * 121 + c + 1] = v.y;
  }
  __syncthreads();
  ushort* dst = xt + (size_t)b * BROW + iq * 64;
#pragma unroll
  for (int q = 0; q < 4; ++q) {        // 960 chunks (120 c x 8 ich), predicated
    const int chunk = q * 256 + t;
    if (chunk < 960) {                 // q=3: waves 0-2 full, wave 3 idle
      const int c = chunk >> 3, ich = chunk & 7;
      u16x8 p;
#pragma unroll
      for (int k = 0; k < 8; ++k) p[k] = f2bf(tl[(ich * 8 + k) * 121 + c]);
      *reinterpret_cast<u16x8*>(dst + (size_t)c * NI + ich * 8) = p;  // 128B runs/8 lanes
    }
  }
}

// ---- pass 2: single-matrix-per-block GEMM (R8-R10 core; b-major addresses).
// block (c, bt): [64 b] x [256 o] x [1 c]; K=256, 4 stages via global_load_lds.
// Epilogue: bf16 IN-PLACE into xt[b][c][o] (exact region this block read).
__global__ __launch_bounds__(256, 4) void e3mix7(ushort* xt,
                                                 const ushort* __restrict__ wb,
                                                 const float* __restrict__ bias0) {
  __shared__ ushort xs[2][64 * 64];    // 2 x 8 KB; row = 64 k (128 B), chunk-swizzled
  const int bid = blockIdx.x;          // 1920 = 16 bt x 120 c, c FASTEST
  const int c  = bid % 120;            //  (bid%8 == c%8 -> W_m pinned per XCD)
  const int bt = bid / 120;
  const int m  = c < 32 ? c : (c < 80 ? 32 + (c - 32) / 3 : 48 + (c - 80) / 5);
  const int bg = bt * 64;

  const int tid = threadIdx.x, lane = tid & 63, wid = tid >> 6;
  const int rb = lane & 15, rg = lane >> 4;
  const int wo = wid * 64;             // wave's o window (4 waves x 64 o)

  // staging: lane l, instr j in {0,1} -> b-row = wid*16 + j*8 + (l>>3),
  // global chunk = (l&7) ^ (row&7); LDS dst linear (HW rule).
  const int srow = wid * 16 + (lane >> 3);
  const ushort* gsrc = xt + (size_t)(bg + srow) * BROW + (size_t)c * NI
                          + ((lane & 7) ^ (srow & 7)) * 8;
  ushort* ldst0 = &xs[0][wid * 1024];
  ushort* ldst1 = &xs[1][wid * 1024];

  f32x4 acc[4][4];                     // [fb][fo]
#pragma unroll
  for (int i = 0; i < 4; ++i)
#pragma unroll
    for (int j = 0; j < 4; ++j) acc[i][j] = (f32x4)0.0f;

#define STAGE(LD, S)                                                          \
  do {                                                                        \
    __builtin_amdgcn_global_load_lds((const AS1 void*)(gsrc + (S) * 64),      \
                                     (AS3 void*)(LD), 16, 0, 0);              \
    __builtin_amdgcn_global_load_lds((const AS1 void*)(gsrc + (S) * 64        \
                                                       + (size_t)8 * BROW),   \
                                     (AS3 void*)((LD) + 512), 16, 0, 0);      \
  } while (0)

  STAGE(ldst0, 0);
  __syncthreads();                     // drains vmcnt: stage 0 ready

#pragma unroll 1
  for (int s = 0; s < 4; ++s) {
    if (s < 3) STAGE((s & 1) ? ldst0 : ldst1, s + 1);   // prefetch next stage
    const ushort* xb = xs[s & 1];
#pragma unroll
    for (int kh = 0; kh < 2; ++kh) {   // two k-halves of 32
      bf16x8 a[4], w[4];
#pragma unroll
      for (int fb = 0; fb < 4; ++fb)   // A frags: LDS, swizzled chunk
        a[fb] = *reinterpret_cast<const bf16x8*>(
            &xb[(fb * 16 + rb) * 64 + (((kh * 4 + rg) ^ (rb & 7)) * 8)]);
#pragma unroll
      for (int fo = 0; fo < 4; ++fo)   // W frags: 256B-coalesced L2 streams
        w[fo] = *reinterpret_cast<const bf16x8*>(
            wb + ((size_t)((m * 32 + s * 8 + kh * 4 + rg) * NO
                           + wo + fo * 16 + rb)) * 8);
#pragma unroll
      for (int fb = 0; fb < 4; ++fb)
#pragma unroll
        for (int fo = 0; fo < 4; ++fo)
          acc[fb][fo] = __builtin_amdgcn_mfma_f32_16x16x32_bf16(a[fb], w[fo],
                                                                acc[fb][fo], 0, 0, 0);
    }
    __syncthreads();                   // drains prefetch; protects buf reuse
  }
#undef STAGE

  if (c < 32) {                        // l=0 irreps: bias b0[c][o]
#pragma unroll
    for (int fo = 0; fo < 4; ++fo) {
      const float bv = bias0[c * NO + wo + fo * 16 + rb];
#pragma unroll
      for (int fb = 0; fb < 4; ++fb) acc[fb][fo] += bv;
    }
  }

  // in-place bf16 store: 16-lane 32B runs (proven class)
#pragma unroll
  for (int fb = 0; fb < 4; ++fb)
#pragma unroll
    for (int r = 0; r < 4; ++r) {
      ushort* ot = xt + (size_t)(bg + fb * 16 + rg * 4 + r) * BROW + (size_t)c * NI;
#pragma unroll
      for (int fo = 0; fo < 4; ++fo)
        ot[wo + fo * 16 + rb] = f2bf(acc[fb][fo][r]);
    }
}

// ---- pass 3: xt [1024 b][120 c][256 o] bf16 -> out [1024 b][256 o][120 c] f32
// Block (b, oh): reads 256B runs (contiguous per c-row half), writes 120 KB/b
// contiguous. LDS tile stride 132 (v2-proven conflict-free both phases).
__global__ __launch_bounds__(256) void otrans(const ushort* __restrict__ xt,
                                              float* __restrict__ out) {
  __shared__ ushort tl[120 * 132];     // 31.7 KB -> 5 blocks/CU
  const int bid = blockIdx.x;          // 2048 = b*2 + oh
  const int b = bid >> 1, oh = bid & 1;
  const int t = threadIdx.x;
  const ushort* src = xt + (size_t)b * BROW + oh * 128;
#pragma unroll
  for (int q = 0; q < 15; ++q) {       // 3840 ushort4 chunks; 256B runs per c
    const int chunk = q * 256 + t;
    const int c = chunk >> 5, o4 = (chunk & 31) * 4;
    ushort4 v = *reinterpret_cast<const ushort4*>(src + (size_t)c * NI + o4);
    *reinterpret_cast<ushort4*>(&tl[c * 132 + o4]) = v;
  }
  __syncthreads();
  const int op = t & 127, ch = t >> 7; // thread: o = oh*128+op, c-half ch
  float* dst = out + ((size_t)b * NO + oh * 128 + op) * NC + ch * 60;
#pragma unroll
  for (int j = 0; j < 15; ++j) {       // 60 c per thread: 240B contiguous run
    float4 v;
    v.x = bf2f(tl[(ch * 60 + 4 * j + 0) * 132 + op]);
    v.y = bf2f(tl[(ch * 60 + 4 * j + 1) * 132 + op]);
    v.z = bf2f(tl[(ch * 60 + 4 * j + 2) * 132 + op]);
    v.w = bf2f(tl[(ch * 60 + 4 * j + 3) * 132 + op]);
    *reinterpret_cast<float4*>(dst + 4 * j) = v;
  }
}

// ---- fallback (small ws): direct strided gather from x, validated in R5 ----
__global__ __launch_bounds__(512, 4) void e3mix2f(const float* __restrict__ x,
                                                  const ushort* __restrict__ wb,
                                                  const float* __restrict__ bias0,
                                                  float* __restrict__ out) {
  __shared__ ushort xs[8 * 16 * 64];
  const int bid = blockIdx.x;          // 960 = 15 ct * 64 bt
  const int ct = bid % 15, bt = bid / 15;
  const int c0 = ct * 8, bg = bt * 16;
  const int t = threadIdx.x, lane = t & 63, wid = t >> 6;
  const int sb = lane >> 2, sp = lane & 3;
  const int rb = lane & 15, rg = lane >> 4;
  const int oc = wid * 16 + rb;
  const int srow = (wid * 16 + sb) * 64;
  const int sk0 = (sp * 16) ^ ((sb & 7) << 3);
  const int sk1 = (sp * 16 + 8) ^ ((sb & 7) << 3);

  f32x4 acc[8][2];
#pragma unroll
  for (int i = 0; i < 8; ++i) { acc[i][0] = (f32x4)0.0f; acc[i][1] = (f32x4)0.0f; }
  bf16x8 w00 = {}, w01 = {}, w10 = {}, w11 = {};

#pragma unroll 1
  for (int s = 0; s < 4; ++s) {
    if (s) __syncthreads();
    u16x8 v0, v1;
    const float* src = x + (size_t)(bg + sb) * (NI * NC)
                         + (size_t)(s * 64 + sp * 16) * NC + (c0 + wid);
#pragma unroll
    for (int jj = 0; jj < 8; ++jj) v0[jj] = f2bf(src[jj * NC]);
#pragma unroll
    for (int jj = 0; jj < 8; ++jj) v1[jj] = f2bf(src[(8 + jj) * NC]);
    *reinterpret_cast<u16x8*>(&xs[srow + sk0]) = v0;
    *reinterpret_cast<u16x8*>(&xs[srow + sk1]) = v1;
    __syncthreads();

    int mprev = -1;
#pragma unroll
    for (int cc = 0; cc < 8; ++cc) {
      const int c = c0 + cc;
      const int m = c < 32 ? c : (c < 80 ? 32 + (c - 32) / 3 : 48 + (c - 80) / 5);
      if (m != mprev) {
        const ushort* wp = wb + ((size_t)((m * 32 + s * 8 + rg) * NO + oc)) * 8;
        w00 = *reinterpret_cast<const bf16x8*>(wp);
        w10 = *reinterpret_cast<const bf16x8*>(wp + (size_t)4 * NO * 8);
        w01 = *reinterpret_cast<const bf16x8*>(wp + 128 * 8);
        w11 = *reinterpret_cast<const bf16x8*>(wp + (size_t)4 * NO * 8 + 128 * 8);
        mprev = m;
      }
      const ushort* xp = xs + (cc * 16 + rb) * 64;
      const int sz = (rb & 7) << 3;
      bf16x8 a0 = *reinterpret_cast<const bf16x8*>(xp + ((rg * 8) ^ sz));
      bf16x8 a1 = *reinterpret_cast<const bf16x8*>(xp + ((32 + rg * 8) ^ sz));
      acc[cc][0] = __builtin_amdgcn_mfma_f32_16x16x32_bf16(a0, w00, acc[cc][0], 0, 0, 0);
      acc[cc][0] = __builtin_amdgcn_mfma_f32_16x16x32_bf16(a1, w10, acc[cc][0], 0, 0, 0);
      acc[cc][1] = __builtin_amdgcn_mfma_f32_16x16x32_bf16(a0, w01, acc[cc][1], 0, 0, 0);
      acc[cc][1] = __builtin_amdgcn_mfma_f32_16x16x32_bf16(a1, w11, acc[cc][1], 0, 0, 0);
    }
  }

  if (c0 < 32) {
#pragma unroll
    for (int cc = 0; cc < 8; ++cc) {
      acc[cc][0] += bias0[(c0 + cc) * NO + oc];
      acc[cc][1] += bias0[(c0 + cc) * NO + oc + 128];
    }
  }

  const int br0 = bg + rg * 4;
#pragma unroll
  for (int of = 0; of < 2; ++of)
#pragma unroll
    for (int r = 0; r < 4; ++r) {
      float4 va = make_float4(acc[0][of][r], acc[1][of][r], acc[2][of][r], acc[3][of][r]);
      float4 vb = make_float4(acc[4][of][r], acc[5][of][r], acc[6][of][r], acc[7][of][r]);
      float* dst = out + ((size_t)(br0 + r) * NO + oc + of * 128) * NC + c0;
      *reinterpret_cast<float4*>(dst) = va;
      *reinterpret_cast<float4*>(dst + 4) = vb;
    }
}

extern "C" void kernel_launch(void* const* d_in, const int* in_sizes, int n_in,
                              void* d_out, int out_size, void* d_ws, size_t ws_size,
                              hipStream_t stream) {
  const float* x  = (const float*)d_in[0];
  const float* w0 = (const float*)d_in[1];
  const float* w1 = (const float*)d_in[2];
  const float* w2 = (const float*)d_in[3];
  const float* b0 = (const float*)d_in[4];
  float* out = (float*)d_out;
  ushort* wb = (ushort*)d_ws;                       // 7.34 MB
  ushort* xt = wb + WELEMS;                         // +62.9 MB (xT, then outT in-place)

  prep_w<<<56 * 32, 256, 0, stream>>>(w0, w1, w2, wb);
  const bool big = ws_size >= (size_t)2 * (WELEMS + XT_ELEMS);
  if (big) {
    xpose<<<4096, 256, 0, stream>>>(x, xt);
    e3mix7<<<16 * 120, 256, 0, stream>>>(xt, wb, b0);
    otrans<<<2048, 256, 0, stream>>>(xt, out);
  } else {
    e3mix2f<<<960, 512, 0, stream>>>(x, wb, b0, out);
  }
}